// Round 4
// baseline (519.830 us; speedup 1.0000x reference)
//
#include <hip/hip_runtime.h>
#include <math.h>

#define BB 32
#define TT 2048
#define VV 1024
#define SS 256
#define TCHUNK 4
#define NSLOT 6

// ---- async global->LDS: per-lane GLOBAL addr, wave-uniform LDS base + lane*size ----
__device__ __forceinline__ void async_ld16(const float* g, const float* l) {
    __builtin_amdgcn_global_load_lds(
        (const __attribute__((address_space(1))) void*)(uintptr_t)g,
        (__attribute__((address_space(3))) void*)(unsigned)(uintptr_t)l, 16, 0, 0);
}
__device__ __forceinline__ void async_ld4(const float* g, const float* l) {
    __builtin_amdgcn_global_load_lds(
        (const __attribute__((address_space(1))) void*)(uintptr_t)g,
        (__attribute__((address_space(3))) void*)(unsigned)(uintptr_t)l, 4, 0, 0);
}
// s_waitcnt simm16: [3:0]=vmcnt lo, [6:4]=expcnt, [11:8]=lgkmcnt, [15:14]=vmcnt hi
#define WAIT_VM0() __builtin_amdgcn_s_waitcnt(0x0F70)   // vmcnt<=0 (producer drains own ops)

// ---- DPP wave_shr1: value from lane-1, lane0 -> 0. One VALU op, no lgkmcnt. ----
__device__ __forceinline__ float dpp_shr1_f(float x) {
    int r = __builtin_amdgcn_update_dpp(0, __float_as_int(x), 0x138, 0xF, 0xF, true);
    return __int_as_float(r);
}
__device__ __forceinline__ int dpp_shr1_i(int x) {
    return __builtin_amdgcn_update_dpp(0, x, 0x138, 0xF, 0xF, true);
}

// Kernel A: G[b][t][j] = (j<Sl)? exp(lp[b][t][tok_j]) : 0  (row = 256 floats)
//           Gbl[b][t]  = exp(lp[b][t][0])  (blank)
__global__ __launch_bounds__(256) void ctc_pre(const float* __restrict__ lp,
    const int* __restrict__ tokens, const int* __restrict__ cqt,
    const int* __restrict__ slen, float* __restrict__ G, float* __restrict__ Gbl,
    float* __restrict__ out)
{
    __shared__ __align__(16) float rows[TCHUNK][VV];
    __shared__ int toks[SS];
    const int tid = threadIdx.x;
    const int bx  = blockIdx.x;
    if (bx == 0 && tid == 0) out[0] = 0.f;   // zero the atomic accumulator (d_out is poisoned)
    const int nchunk = TT / TCHUNK;
    const int b  = bx / nchunk;
    const int t0 = (bx % nchunk) * TCHUNK;
    const int Tl = cqt[b];
    if (t0 >= Tl) return;                    // rows t>=Tl never read (walker clamps to Tl-1)
    const int Sl = slen[b];
    toks[tid] = tokens[b * SS + tid];
#pragma unroll
    for (int k = 0; k < TCHUNK; ++k) {       // stage up to 4 rows, one barrier total
        const int t = t0 + k;
        if (t < Tl)
            ((float4*)rows[k])[tid] = ((const float4*)(lp + ((size_t)b * TT + t) * VV))[tid];
    }
    __syncthreads();
#pragma unroll
    for (int k = 0; k < TCHUNK; ++k) {
        const int t = t0 + k;
        if (t >= Tl) break;                  // uniform across block
        float* gp = G + ((size_t)b * TT + t) * 256;
        gp[tid] = (tid < Sl) ? __expf(rows[k][toks[tid]]) : 0.f;
        if (tid == 0) Gbl[b * TT + t] = __expf(rows[k][0]);
    }
}

// Kernel B: producer-consumer CTC walk, register-double-buffered walker.
//   wave 0  = serial walker; per chunk: poll flag for chunk c+1, ISSUE its 16
//             ds_reads into the idle reg set (no wait), compute chunk c from the
//             full reg set. LDS latency of c+1 hides under compute of c; the
//             only exposed per-chunk cost is the ~130cy flag poll.
//   waves 1-3 = fetchers: chunk c (stride 3) -> 9 global_load_lds into ring slot
//               c%6, own vmcnt(0), then LDS ready-flag.
__global__ __launch_bounds__(256) void ctc_walk(const float* __restrict__ G,
    const float* __restrict__ Gbl, const int* __restrict__ tokens,
    const int* __restrict__ cqt, const int* __restrict__ slen, float* __restrict__ out)
{
    __shared__ __align__(16) float tokL[NSLOT][8 * 256];   // 48 KB ring: 6 slots x 8 rows x 1KB
    __shared__ __align__(16) float blkL[NSLOT][64];        // blank windows
    __shared__ float als[513];
    __shared__ int   aE[65];
    __shared__ int   ready[NSLOT];
    __shared__ int   prog;

    const int b    = blockIdx.x;
    const int tid  = threadIdx.x;
    const int wid  = tid >> 6;
    const int lane = tid & 63;
    const int Tl   = cqt[b];
    const float* __restrict__ Gb   = G   + (size_t)b * TT * 256;
    const float* __restrict__ GblB = Gbl + (size_t)b * TT;

    if (tid < NSLOT) ready[tid] = -1;
    if (tid == NSLOT) prog = -1;
    __syncthreads();                          // only barrier; all 4 waves reach it once

    const int NC = (Tl + 6) >> 3;             // ceil((Tl-1)/8) chunks; t0(c) = 1 + 8c
    volatile int* vready = ready;
    volatile int* vprog  = &prog;

    if (wid != 0) {
        // ---------------- producer waves (1..3) ----------------
        for (int c = wid - 1; c < NC; c += 3) {
            const int slot = c % NSLOT;
            while (*vprog < c - NSLOT) {}     // slot's previous occupant consumed?
            __builtin_amdgcn_sched_barrier(0);
            asm volatile("" ::: "memory");
            const int tbase = 1 + (c << 3);
            const float* lt = tokL[slot];
#pragma unroll
            for (int k = 0; k < 8; ++k) {
                int tt = tbase + k; tt = (tt < Tl) ? tt : (Tl - 1);
                async_ld16(Gb + (size_t)tt * 256 + (lane << 2), lt + k * 256);
            }
            int tbk = tbase + lane; tbk = (tbk < Tl) ? tbk : (Tl - 1);
            async_ld4(GblB + tbk, blkL[slot]);
            WAIT_VM0();                       // own 9 ops landed in LDS
            __builtin_amdgcn_sched_barrier(0);
            asm volatile("" ::: "memory");
            vready[slot] = c;                 // publish
        }
        return;                               // producers exit; no further barriers anywhere
    }

    // ---------------- walker wave (0) ----------------
    const int Sl = slen[b];
    const int j0 = lane * 4;
    const int* tb = tokens + b * SS;
    const int tm1 = (j0 == 0) ? 0 : tb[j0 - 1];
    const int q0 = tb[j0], q1 = tb[j0 + 1], q2 = tb[j0 + 2], q3 = tb[j0 + 3];
    const float m0 = (q0 != tm1) ? 1.f : 0.f;
    const float m1 = (q1 != q0)  ? 1.f : 0.f;
    const float m2 = (q2 != q1)  ? 1.f : 0.f;
    const float m3 = (q3 != q2)  ? 1.f : 0.f;
    const float lzm = (lane == 0) ? 0.f : 1.f;

    float a0=0.f,a1=0.f,a2=0.f,a3=0.f,a4=0.f,a5=0.f,a6=0.f,a7=0.f,aX=0.f;
    if (lane == 0) { a0 = GblB[0]; a1 = Gb[0]; }   // t=0 init
    int   Etot = 0;
    float sfac = lzm;

    // Poll chunk cc's ready flag; fence so no ds_read floats above the flag read.
#define POLL(cc) do { \
    const int s__ = (cc) % NSLOT; \
    while (vready[s__] < (cc)) {} \
    __builtin_amdgcn_sched_barrier(0); \
    asm volatile("" ::: "memory"); \
} while (0)

    // Issue chunk (slot s) LDS->reg reads into buffer X. NO wait here: the
    // compiler places lgkmcnt before first use (next iteration's compute).
#define LOADA(s) do { \
    _Pragma("unroll") \
    for (int k = 0; k < 8; ++k) { \
        prA[k] = ((const float4*)(tokL[s] + (k << 8)))[lane]; \
        pbA[k] = blkL[s][k]; \
    } \
} while (0)
#define LOADB(s) do { \
    _Pragma("unroll") \
    for (int k = 0; k < 8; ++k) { \
        prB[k] = ((const float4*)(tokL[s] + (k << 8)))[lane]; \
        pbB[k] = blkL[s][k]; \
    } \
} while (0)

#define ONESTEP(P4, PB) do { \
    const float pb_ = (PB); \
    const float h1 = dpp_shr1_f(a7) * sfac; \
    const float n0 = pb_ * (a0 + h1); \
    const float n1 = (P4).x * (a1 + a0 + m0 * h1); \
    const float n2 = pb_ * (a2 + a1); \
    const float n3 = (P4).y * (a3 + a2 + m1 * a1); \
    const float n4 = pb_ * (a4 + a3); \
    const float n5 = (P4).z * (a5 + a4 + m2 * a3); \
    const float n6 = pb_ * (a6 + a5); \
    const float n7 = (P4).w * (a7 + a6 + m3 * a5); \
    aX = pb_ * (aX + a7); \
    a0=n0;a1=n1;a2=n2;a3=n3;a4=n4;a5=n5;a6=n6;a7=n7; \
} while (0)

    // Bit-trick renorm (mm never subnormal: p >= e^-16 over 4 steps keeps mm >= 2^-93).
#define RENORM_LOCAL() do { \
    float mm = fmaxf(fmaxf(fmaxf(a0,a1),fmaxf(a2,a3)), fmaxf(fmaxf(a4,a5),fmaxf(a6,a7))); \
    mm = fmaxf(mm, aX); \
    int ee = (__float_as_int(mm) >> 23) - 126; \
    ee = (mm > 0.f) ? ee : 0; \
    const float sc = __int_as_float((127 - ee) << 23); \
    a0*=sc;a1*=sc;a2*=sc;a3*=sc;a4*=sc;a5*=sc;a6*=sc;a7*=sc;aX*=sc; \
    Etot += ee; \
    int Ep = dpp_shr1_i(Etot); \
    if (mm == 0.f && lane > 0) Etot = Ep; \
    Ep = dpp_shr1_i(Etot); \
    if (mm == 0.f && lane > 0) Etot = Ep; \
    int dd = Ep - Etot; \
    dd = (dd < -126) ? -126 : ((dd > 100) ? 100 : dd); \
    sfac = __int_as_float((127 + dd) << 23) * lzm; \
} while (0)

#define COMPUTE_FULL(PR, PB) do { \
    _Pragma("unroll") \
    for (int k = 0; k < 8; ++k) { \
        ONESTEP(PR[k], PB[k]); \
        if (k == 3 || k == 7) RENORM_LOCAL(); \
    } \
} while (0)
#define COMPUTE_TAIL(PR, PB, NV) do { \
    _Pragma("unroll") \
    for (int k = 0; k < 8; ++k) { \
        if (k < (NV)) ONESTEP(PR[k], PB[k]); \
        if (k == 3 || k == 7) RENORM_LOCAL(); \
    } \
} while (0)
#define RELEASE(cc) do { \
    asm volatile("" ::: "memory"); \
    *vprog = (cc); \
} while (0)

    float4 prA[8], prB[8];                       // two reg sets; static index only
    float  pbA[8], pbB[8];

    POLL(0); LOADA(0);
    int c = 0;
    for (;;) {
        // ---- buffer A holds chunk c ----
        if (c + 1 < NC) {
            POLL(c + 1); LOADB((c + 1) % NSLOT); // issue only; hides under compute(A)
            COMPUTE_FULL(prA, pbA);
            RELEASE(c); ++c;
        } else {
            const int nv = (Tl - 1) - (c << 3);  // 1..8
            COMPUTE_TAIL(prA, pbA, nv);
            RELEASE(c);
            break;
        }
        // ---- buffer B holds chunk c ----
        if (c + 1 < NC) {
            POLL(c + 1); LOADA((c + 1) % NSLOT);
            COMPUTE_FULL(prB, pbB);
            RELEASE(c); ++c;
        } else {
            const int nv = (Tl - 1) - (c << 3);
            COMPUTE_TAIL(prB, pbB, nv);
            RELEASE(c);
            break;
        }
    }

    als[8 * lane + 0] = a0; als[8 * lane + 1] = a1;
    als[8 * lane + 2] = a2; als[8 * lane + 3] = a3;
    als[8 * lane + 4] = a4; als[8 * lane + 5] = a5;
    als[8 * lane + 6] = a6; als[8 * lane + 7] = a7;
    aE[lane] = Etot;
    if (lane == 63) { als[512] = aX; aE[64] = Etot; }
    asm volatile("s_waitcnt lgkmcnt(0)" ::: "memory");   // same-wave LDS RAW; no barrier
    if (lane == 0) {
        const int sA = 2 * Sl, sB = 2 * Sl - 1;
        const float vA = als[sA], vB = als[sB];
        const int   eA = aE[sA >> 3], eB = aE[sB >> 3];
        int em;
        if (vA > 0.f && vB > 0.f) em = (eA > eB) ? eA : eB;
        else if (vA > 0.f)        em = eA;
        else if (vB > 0.f)        em = eB;
        else                      em = 0;
        const double s = ldexp((double)vA, eA - em) + ldexp((double)vB, eB - em);
        double loss = -(log(s) + (double)em * 0.6931471805599453);
        if (!(loss < 1e29)) loss = 0.0;
        atomicAdd(out, (float)(loss / ((double)Sl * (double)BB)));
    }
#undef POLL
#undef LOADA
#undef LOADB
#undef ONESTEP
#undef RENORM_LOCAL
#undef COMPUTE_FULL
#undef COMPUTE_TAIL
#undef RELEASE
}

extern "C" void kernel_launch(void* const* d_in, const int* in_sizes, int n_in,
                              void* d_out, int out_size, void* d_ws, size_t ws_size,
                              hipStream_t stream)
{
    const float* lp     = (const float*)d_in[0];
    const int*   tokens = (const int*)d_in[1];
    const int*   cqt    = (const int*)d_in[2];
    const int*   slen   = (const int*)d_in[3];
    float* out = (float*)d_out;
    float* G   = (float*)d_ws;                          // 32*2048*256 floats = 64 MiB
    float* Gbl = G + (size_t)BB * TT * 256;             // 32*2048 floats (walk clamps read-ahead)

    hipLaunchKernelGGL(ctc_pre,  dim3(BB * (TT / TCHUNK)), dim3(256), 0, stream,
                       lp, tokens, cqt, slen, G, Gbl, out);
    hipLaunchKernelGGL(ctc_walk, dim3(BB), dim3(256), 0, stream,
                       G, Gbl, tokens, cqt, slen, out);
}

// Round 5
// 485.970 us; speedup vs baseline: 1.0697x; 1.0697x over previous
//
#include <hip/hip_runtime.h>
#include <math.h>

#define BB 32
#define TT 2048
#define VV 1024
#define SS 256
#define TCHUNK 4
#define CH 16          // walker rows per chunk (halves per-chunk poll/flag overhead)
#define NSLOT 3        // ring slots == producer count; each producer owns one slot

// ---- async global->LDS: per-lane GLOBAL addr, wave-uniform LDS base + lane*size ----
__device__ __forceinline__ void async_ld16(const float* g, const float* l) {
    __builtin_amdgcn_global_load_lds(
        (const __attribute__((address_space(1))) void*)(uintptr_t)g,
        (__attribute__((address_space(3))) void*)(unsigned)(uintptr_t)l, 16, 0, 0);
}
__device__ __forceinline__ void async_ld4(const float* g, const float* l) {
    __builtin_amdgcn_global_load_lds(
        (const __attribute__((address_space(1))) void*)(uintptr_t)g,
        (__attribute__((address_space(3))) void*)(unsigned)(uintptr_t)l, 4, 0, 0);
}
// s_waitcnt simm16: [3:0]=vmcnt lo, [6:4]=expcnt, [11:8]=lgkmcnt, [15:14]=vmcnt hi
#define WAIT_VM0() __builtin_amdgcn_s_waitcnt(0x0F70)   // vmcnt<=0 (producer drains own ops)

// ---- DPP wave_shr1: value from lane-1, lane0 -> 0. One VALU op, no lgkmcnt. ----
__device__ __forceinline__ float dpp_shr1_f(float x) {
    int r = __builtin_amdgcn_update_dpp(0, __float_as_int(x), 0x138, 0xF, 0xF, true);
    return __int_as_float(r);
}
__device__ __forceinline__ int dpp_shr1_i(int x) {
    return __builtin_amdgcn_update_dpp(0, x, 0x138, 0xF, 0xF, true);
}
// 3-input max in one instruction (renorm mm: 9 fmax -> 4 ops)
__device__ __forceinline__ float max3f(float a, float b, float c) {
    float d;
    asm("v_max3_f32 %0, %1, %2, %3" : "=v"(d) : "v"(a), "v"(b), "v"(c));
    return d;
}

// Kernel A: G[b][t][j] = (j<Sl)? exp(lp[t][tok_j] - lp[t][0]) : 0   (r = pe/pb)
//           Gbl[b][t]  = lp[t][0]  (RAW blank logprob; walker sums it, epilogue adds)
// Scaled-variable CTC: alpha_hat = alpha / prod(pb). Even-state updates become pure
// adds in the walker; blank product re-enters the loss as bsum = sum(lp[t][0]).
__global__ __launch_bounds__(256) void ctc_pre(const float* __restrict__ lp,
    const int* __restrict__ tokens, const int* __restrict__ cqt,
    const int* __restrict__ slen, float* __restrict__ G, float* __restrict__ Gbl,
    float* __restrict__ out)
{
    __shared__ __align__(16) float rows[TCHUNK][VV];
    __shared__ int toks[SS];
    const int tid = threadIdx.x;
    const int bx  = blockIdx.x;
    if (bx == 0 && tid == 0) out[0] = 0.f;   // zero the atomic accumulator (d_out is poisoned)
    const int nchunk = TT / TCHUNK;
    const int b  = bx / nchunk;
    const int t0 = (bx % nchunk) * TCHUNK;
    const int Tl = cqt[b];
    if (t0 >= Tl) return;                    // rows t>=Tl never read (walker clamps to Tl-1)
    const int Sl = slen[b];
    toks[tid] = tokens[b * SS + tid];
#pragma unroll
    for (int k = 0; k < TCHUNK; ++k) {       // stage up to 4 rows, one barrier total
        const int t = t0 + k;
        if (t < Tl)
            ((float4*)rows[k])[tid] = ((const float4*)(lp + ((size_t)b * TT + t) * VV))[tid];
    }
    __syncthreads();
#pragma unroll
    for (int k = 0; k < TCHUNK; ++k) {
        const int t = t0 + k;
        if (t >= Tl) break;                  // uniform across block
        const float pb0 = rows[k][0];
        float* gp = G + ((size_t)b * TT + t) * 256;
        gp[tid] = (tid < Sl) ? __expf(rows[k][toks[tid]] - pb0) : 0.f;
        if (tid == 0) Gbl[b * TT + t] = pb0;
    }
}

// Kernel B: producer-consumer CTC walk (scaled variables).
//   wave 0  = serial walker, issue-rate bound -> minimized instruction count:
//             even states n = a + a' (blank factored out), odd n = r*(a+a'+m*a''),
//             renorm mm via v_max3, 16-row chunks (half the poll overhead).
//   waves 1-3 = fetchers: chunk c (stride 3) -> 17 global_load_lds into OWN slot
//               (slot == wid-1 == c%3), own vmcnt(0), then LDS ready-flag.
__global__ __launch_bounds__(256) void ctc_walk(const float* __restrict__ G,
    const float* __restrict__ Gbl, const int* __restrict__ tokens,
    const int* __restrict__ cqt, const int* __restrict__ slen, float* __restrict__ out)
{
    __shared__ __align__(16) float tokL[NSLOT][CH * 256];  // 48 KB ring: 3 slots x 16 rows x 1KB
    __shared__ __align__(16) float blkL[NSLOT][64];        // raw blank windows
    __shared__ float als[513];
    __shared__ int   aE[65];
    __shared__ int   ready[NSLOT];
    __shared__ int   prog;

    const int b    = blockIdx.x;
    const int tid  = threadIdx.x;
    const int wid  = tid >> 6;
    const int lane = tid & 63;
    const int Tl   = cqt[b];
    const float* __restrict__ Gb   = G   + (size_t)b * TT * 256;
    const float* __restrict__ GblB = Gbl + (size_t)b * TT;

    if (tid < NSLOT) ready[tid] = -1;
    if (tid == NSLOT) prog = -1;
    __syncthreads();                          // only barrier; all 4 waves reach it once

    const int NC = (Tl + 14) >> 4;            // ceil((Tl-1)/16) chunks; t0(c) = 1 + 16c
    volatile int* vready = ready;
    volatile int* vprog  = &prog;

    if (wid != 0) {
        // ---------------- producer waves (1..3), fixed slot each ----------------
        const int slot = wid - 1;
        for (int c = wid - 1; c < NC; c += 3) {
            while (*vprog < c - NSLOT) {}     // own slot's previous occupant consumed?
            __builtin_amdgcn_sched_barrier(0);
            asm volatile("" ::: "memory");
            const int tbase = 1 + (c << 4);
            const float* lt = tokL[slot];
#pragma unroll
            for (int k = 0; k < CH; ++k) {
                int tt = tbase + k; tt = (tt < Tl) ? tt : (Tl - 1);
                async_ld16(Gb + (size_t)tt * 256 + (lane << 2), lt + k * 256);
            }
            int tbk = tbase + lane; tbk = (tbk < Tl) ? tbk : (Tl - 1);
            async_ld4(GblB + tbk, blkL[slot]);
            WAIT_VM0();                       // own 17 ops landed in LDS
            __builtin_amdgcn_sched_barrier(0);
            asm volatile("" ::: "memory");
            vready[slot] = c;                 // publish
        }
        return;                               // producers exit; no further barriers anywhere
    }

    // ---------------- walker wave (0) ----------------
    const int Sl = slen[b];
    const int j0 = lane * 4;
    const int* tb = tokens + b * SS;
    const int tm1 = (j0 == 0) ? 0 : tb[j0 - 1];
    const int q0 = tb[j0], q1 = tb[j0 + 1], q2 = tb[j0 + 2], q3 = tb[j0 + 3];
    const float m0 = (q0 != tm1) ? 1.f : 0.f;
    const float m1 = (q1 != q0)  ? 1.f : 0.f;
    const float m2 = (q2 != q1)  ? 1.f : 0.f;
    const float m3 = (q3 != q2)  ? 1.f : 0.f;
    const float lzm = (lane == 0) ? 0.f : 1.f;

    float a0=0.f,a1=0.f,a2=0.f,a3=0.f,a4=0.f,a5=0.f,a6=0.f,a7=0.f,aX=0.f;
    if (lane == 0) {                          // t=0 init: true alpha (B(0)=1)
        const float e0 = __expf(GblB[0]);     // exp(lp[0][0])
        a0 = e0;
        a1 = Gb[0] * e0;                      // r(0,tok0) * exp(lp[0][0]) = exp(lp[0][tok0])
    }
    int    Etot = 0;
    float  sfac = lzm;
    double bacc = 0.0;                        // sum of lp[t][0], t = 1..Tl-1 (exact via f64)

#define LOADCHUNK(s) do { \
    _Pragma("unroll") \
    for (int k = 0; k < CH; ++k) { \
        pr[k] = ((const float4*)(tokL[s] + (k << 8)))[lane]; \
        pb[k] = blkL[s][k]; \
    } \
} while (0)

    // Scaled-variable step: evens are pure adds, odds scaled by r = pe/pb.
#define ONESTEP(P4) do { \
    const float h1 = dpp_shr1_f(a7) * sfac; \
    const float n0 = a0 + h1; \
    const float n1 = (P4).x * (a1 + a0 + m0 * h1); \
    const float n2 = a2 + a1; \
    const float n3 = (P4).y * (a3 + a2 + m1 * a1); \
    const float n4 = a4 + a3; \
    const float n5 = (P4).z * (a5 + a4 + m2 * a3); \
    const float n6 = a6 + a5; \
    const float n7 = (P4).w * (a7 + a6 + m3 * a5); \
    aX = aX + a7; \
    a0=n0;a1=n1;a2=n2;a3=n3;a4=n4;a5=n5;a6=n6;a7=n7; \
} while (0)

    // Bit-trick renorm. Per-4-step drift <= ~40 binades (|lp_tok-lp_blank| <= ~7):
    // inside fp32 normal range and the dd clamp [-126,100].
#define RENORM_LOCAL() do { \
    const float mm = max3f(max3f(a0,a1,a2), max3f(a3,a4,a5), max3f(a6,a7,aX)); \
    int ee = (__float_as_int(mm) >> 23) - 126; \
    ee = (mm > 0.f) ? ee : 0; \
    const float sc = __int_as_float((127 - ee) << 23); \
    a0*=sc;a1*=sc;a2*=sc;a3*=sc;a4*=sc;a5*=sc;a6*=sc;a7*=sc;aX*=sc; \
    Etot += ee; \
    int Ep = dpp_shr1_i(Etot); \
    if (mm == 0.f && lane > 0) Etot = Ep; \
    Ep = dpp_shr1_i(Etot); \
    if (mm == 0.f && lane > 0) Etot = Ep; \
    int dd = Ep - Etot; \
    dd = (dd < -126) ? -126 : ((dd > 100) ? 100 : dd); \
    sfac = __int_as_float((127 + dd) << 23) * lzm; \
} while (0)

    float4 pr[CH];                               // static-index only -> registers
    float  pb[CH];

    const int F = (Tl - 1) >> 4;                 // full chunks; tail nv = (Tl-1)&15
    int slot = 0;
    for (int c = 0; c < NC; ++c) {
        while (vready[slot] < c) {}              // steady state: one poll per 16 steps
        __builtin_amdgcn_sched_barrier(0);       // no ds_read may float above the flag
        asm volatile("" ::: "memory");
        LOADCHUNK(slot);                         // 32 ds ops, latency amortized over 16 steps
        asm volatile("" ::: "memory");
        *vprog = c;                              // slot reusable (reads ordered before this write)
        if (c < F) {
            float bt = ((pb[0]+pb[1])+(pb[2]+pb[3]))+((pb[4]+pb[5])+(pb[6]+pb[7]));
            bt += ((pb[8]+pb[9])+(pb[10]+pb[11]))+((pb[12]+pb[13])+(pb[14]+pb[15]));
            bacc += (double)bt;
#pragma unroll
            for (int k = 0; k < CH; ++k) {
                ONESTEP(pr[k]);
                if ((k & 3) == 3) RENORM_LOCAL();
            }
        } else {                                 // tail chunk (nv in 1..15)
            const int nv = (Tl - 1) - (F << 4);
            float bt = 0.f;
#pragma unroll
            for (int k = 0; k < CH; ++k) {
                if (k < nv) { bt += pb[k]; ONESTEP(pr[k]); }
                if ((k & 3) == 3) RENORM_LOCAL();   // idempotent when nothing changed
            }
            bacc += (double)bt;
        }
        slot = (slot == NSLOT - 1) ? 0 : slot + 1;
    }

    als[8 * lane + 0] = a0; als[8 * lane + 1] = a1;
    als[8 * lane + 2] = a2; als[8 * lane + 3] = a3;
    als[8 * lane + 4] = a4; als[8 * lane + 5] = a5;
    als[8 * lane + 6] = a6; als[8 * lane + 7] = a7;
    aE[lane] = Etot;
    if (lane == 63) { als[512] = aX; aE[64] = Etot; }
    asm volatile("s_waitcnt lgkmcnt(0)" ::: "memory");   // same-wave LDS RAW; no barrier
    if (lane == 0) {
        const int sA = 2 * Sl, sB = 2 * Sl - 1;
        const float vA = als[sA], vB = als[sB];
        const int   eA = aE[sA >> 3], eB = aE[sB >> 3];
        int em;
        if (vA > 0.f && vB > 0.f) em = (eA > eB) ? eA : eB;
        else if (vA > 0.f)        em = eA;
        else if (vB > 0.f)        em = eB;
        else                      em = 0;
        const double s = ldexp((double)vA, eA - em) + ldexp((double)vB, eB - em);
        // log alpha = log(s) + em*ln2 + sum(lp[t][0])  (blank product restored)
        double loss = -(log(s) + (double)em * 0.6931471805599453 + bacc);
        if (!(loss < 1e29)) loss = 0.0;
        atomicAdd(out, (float)(loss / ((double)Sl * (double)BB)));
    }
#undef LOADCHUNK
#undef ONESTEP
#undef RENORM_LOCAL
}

extern "C" void kernel_launch(void* const* d_in, const int* in_sizes, int n_in,
                              void* d_out, int out_size, void* d_ws, size_t ws_size,
                              hipStream_t stream)
{
    const float* lp     = (const float*)d_in[0];
    const int*   tokens = (const int*)d_in[1];
    const int*   cqt    = (const int*)d_in[2];
    const int*   slen   = (const int*)d_in[3];
    float* out = (float*)d_out;
    float* G   = (float*)d_ws;                          // 32*2048*256 floats = 64 MiB
    float* Gbl = G + (size_t)BB * TT * 256;             // 32*2048 floats (walk clamps read-ahead)

    hipLaunchKernelGGL(ctc_pre,  dim3(BB * (TT / TCHUNK)), dim3(256), 0, stream,
                       lp, tokens, cqt, slen, G, Gbl, out);
    hipLaunchKernelGGL(ctc_walk, dim3(BB), dim3(256), 0, stream,
                       G, Gbl, tokens, cqt, slen, out);
}

// Round 6
// 466.720 us; speedup vs baseline: 1.1138x; 1.0412x over previous
//
#include <hip/hip_runtime.h>
#include <math.h>

#define BB 32
#define TT 2048
#define VV 1024
#define SS 256
#define TCHUNK 4
#define CH 16          // walker rows per chunk
#define NSLOT 3        // ring slots == producer count; each producer owns one slot

// ---- async global->LDS: per-lane GLOBAL addr, wave-uniform LDS base + lane*size ----
__device__ __forceinline__ void async_ld16(const float* g, const float* l) {
    __builtin_amdgcn_global_load_lds(
        (const __attribute__((address_space(1))) void*)(uintptr_t)g,
        (__attribute__((address_space(3))) void*)(unsigned)(uintptr_t)l, 16, 0, 0);
}
__device__ __forceinline__ void async_ld4(const float* g, const float* l) {
    __builtin_amdgcn_global_load_lds(
        (const __attribute__((address_space(1))) void*)(uintptr_t)g,
        (__attribute__((address_space(3))) void*)(unsigned)(uintptr_t)l, 4, 0, 0);
}
// s_waitcnt simm16: [3:0]=vmcnt lo, [6:4]=expcnt, [11:8]=lgkmcnt, [15:14]=vmcnt hi
#define WAIT_VM0() __builtin_amdgcn_s_waitcnt(0x0F70)   // vmcnt<=0 (producer drains own ops)

// ---- DPP wave_shr1: value from lane-1, lane0 -> 0. One VALU op, no lgkmcnt. ----
__device__ __forceinline__ float dpp_shr1_f(float x) {
    int r = __builtin_amdgcn_update_dpp(0, __float_as_int(x), 0x138, 0xF, 0xF, true);
    return __int_as_float(r);
}
__device__ __forceinline__ int dpp_shr1_i(int x) {
    return __builtin_amdgcn_update_dpp(0, x, 0x138, 0xF, 0xF, true);
}
// 3-input max in one instruction
__device__ __forceinline__ float max3f(float a, float b, float c) {
    float d;
    asm("v_max3_f32 %0, %1, %2, %3" : "=v"(d) : "v"(a), "v"(b), "v"(c));
    return d;
}

// Kernel A: G[b][t][j] = (j<Sl)? exp(lp[t][tok_j] - lp[t][0]) : 0   (r = pe/pb)
//           Gbl[b][t]  = lp[t][0]  (RAW blank logprob; walker sums it, epilogue adds)
__global__ __launch_bounds__(256) void ctc_pre(const float* __restrict__ lp,
    const int* __restrict__ tokens, const int* __restrict__ cqt,
    const int* __restrict__ slen, float* __restrict__ G, float* __restrict__ Gbl,
    float* __restrict__ out)
{
    __shared__ __align__(16) float rows[TCHUNK][VV];
    __shared__ int toks[SS];
    const int tid = threadIdx.x;
    const int bx  = blockIdx.x;
    if (bx == 0 && tid == 0) out[0] = 0.f;   // zero the atomic accumulator (d_out is poisoned)
    const int nchunk = TT / TCHUNK;
    const int b  = bx / nchunk;
    const int t0 = (bx % nchunk) * TCHUNK;
    const int Tl = cqt[b];
    if (t0 >= Tl) return;                    // rows t>=Tl never read (walker clamps to Tl-1)
    const int Sl = slen[b];
    toks[tid] = tokens[b * SS + tid];
#pragma unroll
    for (int k = 0; k < TCHUNK; ++k) {       // stage up to 4 rows, one barrier total
        const int t = t0 + k;
        if (t < Tl)
            ((float4*)rows[k])[tid] = ((const float4*)(lp + ((size_t)b * TT + t) * VV))[tid];
    }
    __syncthreads();
#pragma unroll
    for (int k = 0; k < TCHUNK; ++k) {
        const int t = t0 + k;
        if (t >= Tl) break;                  // uniform across block
        const float pb0 = rows[k][0];
        float* gp = G + ((size_t)b * TT + t) * 256;
        gp[tid] = (tid < Sl) ? __expf(rows[k][toks[tid]] - pb0) : 0.f;
        if (tid == 0) Gbl[b * TT + t] = pb0;
    }
}

// Kernel B: producer-consumer CTC walk, TWO systolic walker waves (state split).
//   wave 0 (A) = states 0..255  (tokens 0..127). Runs ahead; per step publishes its
//                top state (lane63 a3) to an LDS halo ring + per-renorm exponent EA.
//   wave 1 (B) = states 256..512 (tokens 128..255) + aX. Lags A by one chunk;
//                lane0's left-neighbor value/exponent come from A's halo ring.
//   waves 2-4  = fetchers (unchanged): chunk c -> 17 global_load_lds into own slot,
//                vmcnt(0), ready-flag.
// Dependencies flow strictly upward (state s needs s,s-1,s-2), so A never waits
// on B; B's exponent reconciliation: A's renorm at k=4g+3 precedes B's group g+1
// boundary, so all halos consumed in one B sfac-group share exponent EA[g].
// All renorm scalings are exact powers of 2 -> bit-identical to the fused version.
__global__ __launch_bounds__(320) void ctc_walk(const float* __restrict__ G,
    const float* __restrict__ Gbl, const int* __restrict__ tokens,
    const int* __restrict__ cqt, const int* __restrict__ slen, float* __restrict__ out)
{
    __shared__ __align__(16) float tokL[NSLOT][CH * 256];  // 48 KB ring
    __shared__ __align__(16) float blkL[NSLOT][64];        // raw blank windows
    __shared__ float hbuf[2][CH][64];                      // halo ring (A's a3), ping-pong
    __shared__ int   eabuf[2][4][64];                      // A's Etot after renorm g
    __shared__ float als[513];
    __shared__ int   aE[129];
    __shared__ double baccS;
    __shared__ int   ready[NSLOT];
    __shared__ int   prog, hready, afin;

    const int b    = blockIdx.x;
    const int tid  = threadIdx.x;
    const int wid  = tid >> 6;
    const int lane = tid & 63;
    const int Tl   = cqt[b];
    const float* __restrict__ Gb   = G   + (size_t)b * TT * 256;
    const float* __restrict__ GblB = Gbl + (size_t)b * TT;

    if (tid < NSLOT) ready[tid] = -1;
    if (tid == NSLOT)     prog   = -1;
    if (tid == NSLOT + 1) hready = -1;
    if (tid == NSLOT + 2) afin   = 0;
    __syncthreads();                          // only barrier; all 5 waves reach it once

    const int NC = (Tl + 14) >> 4;            // ceil((Tl-1)/16); t0(c) = 1 + 16c
    const int F  = (Tl - 1) >> 4;             // full chunks; tail nv = (Tl-1)&15
    volatile int* vready  = ready;
    volatile int* vprog   = &prog;
    volatile int* vhready = &hready;
    volatile int* vafin   = &afin;

    if (wid >= 2) {
        // ---------------- producer waves (2..4), fixed slot each ----------------
        const int slot = wid - 2;
        for (int c = slot; c < NC; c += 3) {
            while (*vprog < c - NSLOT) {}     // own slot's previous occupant consumed (by B)?
            __builtin_amdgcn_sched_barrier(0);
            asm volatile("" ::: "memory");
            const int tbase = 1 + (c << 4);
            const float* lt = tokL[slot];
#pragma unroll
            for (int k = 0; k < CH; ++k) {
                int tt = tbase + k; tt = (tt < Tl) ? tt : (Tl - 1);
                async_ld16(Gb + (size_t)tt * 256 + (lane << 2), lt + k * 256);
            }
            int tbk = tbase + lane; tbk = (tbk < Tl) ? tbk : (Tl - 1);
            async_ld4(GblB + tbk, blkL[slot]);
            WAIT_VM0();                       // own 17 ops landed in LDS
            __builtin_amdgcn_sched_barrier(0);
            asm volatile("" ::: "memory");
            vready[slot] = c;                 // publish
        }
        return;
    }

    const int Sl = slen[b];
    const int* tb = tokens + b * SS;

    if (wid == 0) {
        // ================= walker A: states 0..255, tokens 0..127 =================
        const int jA  = lane * 2;
        const int tm1 = (lane == 0) ? 0 : tb[jA - 1];
        const int q0 = tb[jA], q1 = tb[jA + 1];
        const float m0 = (q0 != tm1) ? 1.f : 0.f;
        const float m1 = (q1 != q0)  ? 1.f : 0.f;
        const float lzm = (lane == 0) ? 0.f : 1.f;

        float a0=0.f,a1=0.f,a2=0.f,a3=0.f;
        if (lane == 0) {                      // t=0 init: true alpha (B(0)=1)
            const float e0 = __expf(GblB[0]);
            a0 = e0;
            a1 = Gb[0] * e0;
        }
        int    Etot = 0;
        float  sfac = lzm;
        double bacc = 0.0;

#define ONESTEP_A(P2) do { \
    const float h1 = dpp_shr1_f(a3) * sfac; \
    const float n0 = a0 + h1; \
    const float n1 = (P2).x * (a1 + a0 + m0 * h1); \
    const float n2 = a2 + a1; \
    const float n3 = (P2).y * (a3 + a2 + m1 * a1); \
    a0=n0;a1=n1;a2=n2;a3=n3; \
} while (0)

#define RENORM_A() do { \
    const float mm = fmaxf(max3f(a0,a1,a2), a3); \
    int ee = (__float_as_int(mm) >> 23) - 126; \
    ee = (mm > 0.f) ? ee : 0; \
    const float sc = __int_as_float((127 - ee) << 23); \
    a0*=sc;a1*=sc;a2*=sc;a3*=sc; \
    Etot += ee; \
    int Ep = dpp_shr1_i(Etot); \
    if (mm == 0.f && lane > 0) Etot = Ep; \
    Ep = dpp_shr1_i(Etot); \
    if (mm == 0.f && lane > 0) Etot = Ep; \
    int dd = Ep - Etot; \
    dd = (dd < -126) ? -126 : ((dd > 100) ? 100 : dd); \
    sfac = __int_as_float((127 + dd) << 23) * lzm; \
} while (0)

        float2 pr[CH];                        // static-index only -> registers
        float  pb[CH];
        int slot = 0;
        for (int c = 0; c < NC; ++c) {
            while (vready[slot] < c) {}       // chunk staged by producer
            while (*vprog < c - 2) {}         // bound lead over B (halo ping-pong safety)
            __builtin_amdgcn_sched_barrier(0);
            asm volatile("" ::: "memory");
#pragma unroll
            for (int k = 0; k < CH; ++k) {
                pr[k] = *(const float2*)(tokL[slot] + (k << 8) + (lane << 1));
                pb[k] = blkL[slot][k];
            }
            const int par = c & 1;
            float* hb = &hbuf[par][0][0];
            int*   eb = &eabuf[par][0][0];
            if (c < F) {
                float bt = ((pb[0]+pb[1])+(pb[2]+pb[3]))+((pb[4]+pb[5])+(pb[6]+pb[7]));
                bt += ((pb[8]+pb[9])+(pb[10]+pb[11]))+((pb[12]+pb[13])+(pb[14]+pb[15]));
                bacc += (double)bt;
#pragma unroll
                for (int k = 0; k < CH; ++k) {
                    ONESTEP_A(pr[k]);
                    if ((k & 3) == 3) { RENORM_A(); eb[((k >> 2) << 6) + lane] = Etot; }
                    hb[(k << 6) + lane] = a3;     // post-renorm top state -> halo
                }
            } else {                          // tail chunk (nv in 1..15)
                const int nv = (Tl - 1) - (F << 4);
                float bt = 0.f;
#pragma unroll
                for (int k = 0; k < CH; ++k) {
                    if (k < nv) { bt += pb[k]; ONESTEP_A(pr[k]); }
                    if ((k & 3) == 3) { RENORM_A(); eb[((k >> 2) << 6) + lane] = Etot; }
                    hb[(k << 6) + lane] = a3;
                }
                bacc += (double)bt;
            }
            asm volatile("" ::: "memory");
            *vhready = c;                     // LDS in-order: halos/EA landed first
            slot = (slot == NSLOT - 1) ? 0 : slot + 1;
        }
        als[4 * lane + 0] = a0; als[4 * lane + 1] = a1;
        als[4 * lane + 2] = a2; als[4 * lane + 3] = a3;
        aE[lane] = Etot;
        if (lane == 0) baccS = bacc;
        asm volatile("s_waitcnt lgkmcnt(0)" ::: "memory");
        *vafin = 1;
        return;
#undef ONESTEP_A
#undef RENORM_A
    }

    // ================= walker B: states 256..512, tokens 128..255 =================
    {
        const int jB  = 128 + lane * 2;
        const int q0 = tb[jB], q1 = tb[jB + 1];
        const int tm1 = tb[jB - 1];
        const float m0 = (q0 != tm1) ? 1.f : 0.f;
        const float m1 = (q1 != q0)  ? 1.f : 0.f;

        float a0=0.f,a1=0.f,a2=0.f,a3=0.f,aX=0.f;
        int   Etot = 0;
        float sfac = 1.f;                     // lane0 HAS a left neighbor (A lane63)
        float hprev = 0.f;                    // A's top state at previous step

#define ONESTEP_B(P2, HIN) do { \
    float hx = dpp_shr1_f(a3); \
    hx = (lane == 0) ? (HIN) : hx; \
    const float h1 = hx * sfac; \
    const float n0 = a0 + h1; \
    const float n1 = (P2).x * (a1 + a0 + m0 * h1); \
    const float n2 = a2 + a1; \
    const float n3 = (P2).y * (a3 + a2 + m1 * a1); \
    aX = aX + a3; \
    a0=n0;a1=n1;a2=n2;a3=n3; \
} while (0)

#define RENORM_B(g) do { \
    const float mm = fmaxf(max3f(a0,a1,a2), fmaxf(a3,aX)); \
    int ee = (__float_as_int(mm) >> 23) - 126; \
    ee = (mm > 0.f) ? ee : 0; \
    const float sc = __int_as_float((127 - ee) << 23); \
    a0*=sc;a1*=sc;a2*=sc;a3*=sc;aX*=sc; \
    Etot += ee; \
    int Ep = dpp_shr1_i(Etot); \
    Ep = (lane == 0) ? ea[g] : Ep; \
    if (mm == 0.f) Etot = Ep; \
    Ep = dpp_shr1_i(Etot); \
    Ep = (lane == 0) ? ea[g] : Ep; \
    if (mm == 0.f) Etot = Ep; \
    int dd = Ep - Etot; \
    dd = (dd < -126) ? -126 : ((dd > 100) ? 100 : dd); \
    sfac = __int_as_float((127 + dd) << 23); \
} while (0)

        float2 pr[CH];
        float  hk[CH];
        int    ea[4];
        int slot = 0;
        for (int c = 0; c < NC; ++c) {
            while (*vhready < c) {}           // A done chunk c => producer data + halos ready
            __builtin_amdgcn_sched_barrier(0);
            asm volatile("" ::: "memory");
            const int par = c & 1;
#pragma unroll
            for (int k = 0; k < CH; ++k) {
                pr[k] = *(const float2*)(tokL[slot] + (k << 8) + 128 + (lane << 1));
                hk[k] = hbuf[par][k][63];     // uniform addr -> broadcast
            }
#pragma unroll
            for (int g = 0; g < 4; ++g) ea[g] = eabuf[par][g][63];
            asm volatile("" ::: "memory");
            *vprog = c;                       // slot reusable (reads ordered before this write)
            if (c < F) {
#pragma unroll
                for (int k = 0; k < CH; ++k) {
                    ONESTEP_B(pr[k], (k == 0) ? hprev : hk[k - 1]);
                    if ((k & 3) == 3) RENORM_B(k >> 2);
                }
                hprev = hk[CH - 1];
            } else {
                const int nv = (Tl - 1) - (F << 4);
#pragma unroll
                for (int k = 0; k < CH; ++k) {
                    if (k < nv) ONESTEP_B(pr[k], (k == 0) ? hprev : hk[k - 1]);
                    if ((k & 3) == 3) RENORM_B(k >> 2);
                }
            }
            slot = (slot == NSLOT - 1) ? 0 : slot + 1;
        }

        als[256 + 4 * lane + 0] = a0; als[256 + 4 * lane + 1] = a1;
        als[256 + 4 * lane + 2] = a2; als[256 + 4 * lane + 3] = a3;
        aE[64 + lane] = Etot;
        if (lane == 63) { als[512] = aX; aE[128] = Etot; }
        asm volatile("s_waitcnt lgkmcnt(0)" ::: "memory");
        while (*vafin == 0) {}                // A's als/aE/baccS visible after this
        asm volatile("" ::: "memory");
        if (lane == 0) {
            const int sA = 2 * Sl, sB = 2 * Sl - 1;
            const float vA = als[sA], vB = als[sB];
            const int   eA = aE[sA >> 2], eB = aE[sB >> 2];
            int em;
            if (vA > 0.f && vB > 0.f) em = (eA > eB) ? eA : eB;
            else if (vA > 0.f)        em = eA;
            else if (vB > 0.f)        em = eB;
            else                      em = 0;
            const double s = ldexp((double)vA, eA - em) + ldexp((double)vB, eB - em);
            // log alpha = log(s) + em*ln2 + sum(lp[t][0])  (blank product restored)
            double loss = -(log(s) + (double)em * 0.6931471805599453 + baccS);
            if (!(loss < 1e29)) loss = 0.0;
            atomicAdd(out, (float)(loss / ((double)Sl * (double)BB)));
        }
#undef ONESTEP_B
#undef RENORM_B
    }
}

extern "C" void kernel_launch(void* const* d_in, const int* in_sizes, int n_in,
                              void* d_out, int out_size, void* d_ws, size_t ws_size,
                              hipStream_t stream)
{
    const float* lp     = (const float*)d_in[0];
    const int*   tokens = (const int*)d_in[1];
    const int*   cqt    = (const int*)d_in[2];
    const int*   slen   = (const int*)d_in[3];
    float* out = (float*)d_out;
    float* G   = (float*)d_ws;                          // 32*2048*256 floats = 64 MiB
    float* Gbl = G + (size_t)BB * TT * 256;             // 32*2048 floats (walk clamps read-ahead)

    hipLaunchKernelGGL(ctc_pre,  dim3(BB * (TT / TCHUNK)), dim3(256), 0, stream,
                       lp, tokens, cqt, slen, G, Gbl, out);
    hipLaunchKernelGGL(ctc_walk, dim3(BB), dim3(320), 0, stream,
                       G, Gbl, tokens, cqt, slen, out);
}